// Round 10
// baseline (146.723 us; speedup 1.0000x reference)
//
#include <hip/hip_runtime.h>
#include <math.h>

// ===== MEASUREMENT BUILD (R10): k1 launched 17x (idempotent) to measure
// its real per-dispatch cost from dur_us: k1+ov = (T - 26.7)/16.
// Kernels are byte-identical to R9. Revert to 1x after reading.
constexpr int K1_LAUNCHES = 17;

// Problem constants (fixed by the reference)
constexpr int B_    = 8;
constexpr int CIN_  = 128;
constexpr int H_    = 28;
constexpr int W_    = 28;
constexpr int COUT_ = 256;
constexpr int OH_   = 28;
constexpr int OW_   = 28;
constexpr int L_    = OH_ * OW_;     // 784
constexpr int N_    = B_ * L_;       // 6272
constexpr int NCB_  = 64;
constexpr int K_    = 16;
constexpr int SUB_  = 18;            // 2 channels x 9 taps

// ws layout (byte offsets). idx layout [cb][n] (cb-major).
constexpr size_t WS_IDX  = 0;                  // 64*6272 uchar = 401408 B
constexpr size_t WS_LUT8 = 0x100000;           // 262144 uchar = 256 KB
constexpr size_t WS_BF2  = 0x180000;           // 256 f32 (bias + folded consts)

// ---------------------------------------------------------------------------
// K1: fused phase1 + pack (identical to R9).
// ---------------------------------------------------------------------------
__global__ __launch_bounds__(256, 2) void amm_k1(
    const int* __restrict__ x_q, const int* __restrict__ x_z,
    const int* __restrict__ c_q, const float* __restrict__ c_s,
    const int* __restrict__ c_z, const float* __restrict__ x_s,
    const int* __restrict__ lut_q, const float* __restrict__ lut_s,
    const int* __restrict__ lut_z,
    const int* __restrict__ bias_q, const float* __restrict__ bias_s,
    const int* __restrict__ bias_z,
    unsigned char* __restrict__ idx8, unsigned char* __restrict__ lut8,
    float* __restrict__ biasf2)
{
    const int bx  = blockIdx.x;
    const int tid = threadIdx.x;

    if (bx >= 512) {                       // ---- pack role ----
        const int pb = bx - 512;
        if (pb < 256) {
            const int i = pb * 1024 + tid * 4;       // covers 262144 exactly
            const int4 v = *(const int4*)(lut_q + i);
            uchar4 o;
            o.x = (unsigned char)(v.x + 128);
            o.y = (unsigned char)(v.y + 128);
            o.z = (unsigned char)(v.z + 128);
            o.w = (unsigned char)(v.w + 128);
            *(uchar4*)(lut8 + i) = o;
        } else {
            const double ls = (double)lut_s[0];
            const double c0 = (8192.0 + 64.0 * (double)lut_z[0]) * ls;
            biasf2[tid] = (float)((double)(bias_q[tid] - bias_z[0]) *
                                  (double)bias_s[0] - c0);
        }
        return;
    }

    // ---- argmin role ----
    const int cb = bx & 63;
    const int b  = bx >> 6;

    __shared__ float sx[2][900];     // 30x30 zero-padded, 7.2 KB
    __shared__ float c_lds[288];     // [s][k] k-major, float(c_q - zc)
    __shared__ float y2_lds[16];

    const int zc = c_z[cb];
    for (int i = tid; i < 1800; i += 256) ((float*)sx)[i] = 0.0f;
    for (int i = tid; i < 288; i += 256) {
        const int k = i / SUB_, s = i - k * SUB_;
        c_lds[s * 16 + k] = (float)(c_q[cb * 288 + i] - zc);   // exact int
    }
    __syncthreads();

    const int xz = x_z[0];
    for (int i = tid; i < 2 * 784; i += 256) {
        const int c2 = i >= 784;
        const int r  = i - c2 * 784;
        const int h  = r / 28;
        const int w  = r - h * 28;
        sx[c2][(h + 1) * 30 + (w + 1)] =
            (float)(x_q[(size_t)(b * CIN_ + 2 * cb + c2) * L_ + r] - xz);
    }
    if (tid < 16) {                 // y2 in double, same order as before
        const double csf = (double)c_s[cb];
        const double den = (double)x_s[0] * csf;
        double s2 = 0.0;
        for (int s = 0; s < SUB_; ++s) {
            const double d = (double)c_lds[s * 16 + tid] * csf;
            s2 += d * d;
        }
        y2_lds[tid] = (float)(int)rint(s2 / den);   // < 2^24 -> exact in f32
    }
    __syncthreads();

    if (tid < 196) {
        float tap[4][SUB_];
        int   posr[4];
        #pragma unroll
        for (int ps = 0; ps < 4; ++ps) {
            const int p  = tid + 196 * ps;
            posr[ps] = p;
            const int oh = p / 28;
            const int ow = p - oh * 28;
            const int base = oh * 30 + ow;
            #pragma unroll
            for (int c2 = 0; c2 < 2; ++c2)
                #pragma unroll
                for (int kh = 0; kh < 3; ++kh)
                    #pragma unroll
                    for (int kw = 0; kw < 3; ++kw)
                        tap[ps][c2 * 9 + kh * 3 + kw] =
                            sx[c2][base + kh * 30 + kw];
        }

        float bestd[4] = {3.0e38f, 3.0e38f, 3.0e38f, 3.0e38f};
        int   bestk[4] = {0, 0, 0, 0};

        #pragma unroll
        for (int kc = 0; kc < 4; ++kc) {
            float acc[4][4];
            #pragma unroll
            for (int ps = 0; ps < 4; ++ps)
                #pragma unroll
                for (int kk = 0; kk < 4; ++kk) acc[ps][kk] = 0.0f;

            #pragma unroll
            for (int s = 0; s < SUB_; ++s) {
                const float4 c4 = *(const float4*)&c_lds[s * 16 + kc * 4];
                #pragma unroll
                for (int ps = 0; ps < 4; ++ps) {
                    const float xs = tap[ps][s];
                    acc[ps][0] = fmaf(xs, c4.x, acc[ps][0]);
                    acc[ps][1] = fmaf(xs, c4.y, acc[ps][1]);
                    acc[ps][2] = fmaf(xs, c4.z, acc[ps][2]);
                    acc[ps][3] = fmaf(xs, c4.w, acc[ps][3]);
                }
            }
            #pragma unroll
            for (int kk = 0; kk < 4; ++kk) {
                const float yk = y2_lds[kc * 4 + kk];
                #pragma unroll
                for (int ps = 0; ps < 4; ++ps) {
                    const float d = fmaf(-2.0f, acc[ps][kk], yk);
                    if (d < bestd[ps]) { bestd[ps] = d; bestk[ps] = kc * 4 + kk; }
                }
            }
        }

        unsigned char* op = idx8 + (size_t)cb * N_ + b * L_;
        #pragma unroll
        for (int ps = 0; ps < 4; ++ps)
            op[posr[ps]] = (unsigned char)bestk[ps];
    }
}

// ---------------------------------------------------------------------------
// K2 (identical to R9): per-wave position, biased-uint8 LUT gather,
// packed-u16 carry-free accumulation, LDS transpose, int4 stores.
// ---------------------------------------------------------------------------
__global__ __launch_bounds__(256, 6) void amm_phase2(
    const unsigned char* __restrict__ idx8, const unsigned char* __restrict__ lut8,
    const float* __restrict__ lut_s, const float* __restrict__ biasf2,
    const float* __restrict__ out_s, const int* __restrict__ out_z,
    int* __restrict__ out)
{
    const int tid  = threadIdx.x;
    const int lane = tid & 63;
    const int w    = __builtin_amdgcn_readfirstlane(tid >> 6);
    const int nb   = blockIdx.x * 4;
    const int b    = nb / L_;
    const int r0   = nb - b * L_;
    const int pos  = w;
    const int sh   = 8 * pos;

    __shared__ unsigned int res[4][130];

    unsigned int accLo = 0, accHi = 0;
    #pragma unroll
    for (int bt = 0; bt < 4; ++bt) {
        unsigned int kw[16];
        #pragma unroll
        for (int i = 0; i < 16; ++i) {
            const int cbi = bt * 16 + i;
            kw[i] = *(const unsigned int*)(idx8 + (size_t)cbi * N_ + nb);
        }
        unsigned int t[16];
        #pragma unroll
        for (int i = 0; i < 16; ++i) {
            const unsigned int k = (kw[i] >> sh) & 0xffu;
            const int cbi = bt * 16 + i;
            t[i] = *(const unsigned int*)(lut8 +
                    ((size_t)((cbi << 4) + k) << 8) + (lane << 2));
        }
        #pragma unroll
        for (int i = 0; i < 16; ++i) {
            accLo += t[i] & 0x00FF00FFu;
            accHi += (t[i] >> 8) & 0x00FF00FFu;
        }
    }

    res[pos][lane * 2]     = accLo;
    res[pos][lane * 2 + 1] = accHi;
    __syncthreads();

    const float lsf = lut_s[0];
    const float osf = out_s[0];
    const float ozf = (float)out_z[0];

    const int co   = tid;
    const int c    = co & 3;
    const int u    = (co >> 2) * 2 + (c & 1);
    const int half = c >> 1;
    const float bf = biasf2[co];

    int4 ov;
    int* ovp = (int*)&ov;
    #pragma unroll
    for (int p = 0; p < 4; ++p) {
        const unsigned int vv = res[p][u];
        const int sv = (int)((vv >> (16 * half)) & 0xffffu);
        float f = (float)sv * lsf + bf;
        f = fmaxf(f, 0.0f) / osf + ozf;
        f = fminf(fmaxf(f, -128.0f), 127.0f);
        ovp[p] = (int)rintf(f);
    }
    *(int4*)(out + (size_t)(b * COUT_ + co) * L_ + r0) = ov;
}

extern "C" void kernel_launch(void* const* d_in, const int* in_sizes, int n_in,
                              void* d_out, int out_size, void* d_ws, size_t ws_size,
                              hipStream_t stream)
{
    const int*   x_q    = (const int*)  d_in[0];
    const float* x_s    = (const float*)d_in[1];
    const int*   x_z    = (const int*)  d_in[2];
    const int*   c_q    = (const int*)  d_in[3];
    const float* c_s    = (const float*)d_in[4];
    const int*   c_z    = (const int*)  d_in[5];
    const int*   lut_q  = (const int*)  d_in[6];
    const float* lut_s  = (const float*)d_in[7];
    const int*   lut_z  = (const int*)  d_in[8];
    const int*   bias_q = (const int*)  d_in[9];
    const float* bias_s = (const float*)d_in[10];
    const int*   bias_z = (const int*)  d_in[11];
    const float* out_s  = (const float*)d_in[12];
    const int*   out_z  = (const int*)  d_in[13];

    char* ws = (char*)d_ws;
    unsigned char* idx8 = (unsigned char*)(ws + WS_IDX);
    unsigned char* lut8 = (unsigned char*)(ws + WS_LUT8);
    float* biasf2 = (float*)(ws + WS_BF2);

    // k1 is idempotent: launching it 17x is deterministic and measures
    // its real per-dispatch cost via dur_us.
    for (int it = 0; it < K1_LAUNCHES; ++it)
        amm_k1<<<dim3(769), 256, 0, stream>>>(x_q, x_z, c_q, c_s, c_z, x_s,
                                              lut_q, lut_s, lut_z,
                                              bias_q, bias_s, bias_z,
                                              idx8, lut8, biasf2);

    amm_phase2<<<dim3(N_ / 4), 256, 0, stream>>>(
        idx8, lut8, lut_s, biasf2, out_s, out_z, (int*)d_out);
}